// Round 3
// baseline (1441.588 us; speedup 1.0000x reference)
//
#include <hip/hip_runtime.h>
#include <hip/hip_bf16.h>
#include <hip/hip_fp16.h>

// Problem dims (fixed for QuantLlamaMLP_549755813920)
#define T_TOK 4096   // tokens = 2*2048
#define KDIM  4096   // in_features
#define IDIM  11008  // intermediate
#define ODIM  4096   // out_features

typedef _Float16 f16x8 __attribute__((ext_vector_type(8)));
typedef __fp16   h16x2 __attribute__((ext_vector_type(2)));  // cvt_pkrtz return type
typedef float    f32x4 __attribute__((ext_vector_type(4)));
typedef float    f32x2 __attribute__((ext_vector_type(2)));

// async global->LDS, 16B per lane; LDS dest = wave-uniform base + lane*16
__device__ __forceinline__ void glds16(const void* g, void* l) {
  __builtin_amdgcn_global_load_lds(
      (const __attribute__((address_space(1))) void*)g,
      (__attribute__((address_space(3))) void*)l, 16, 0, 0);
}

// ---------------- x: f32 -> f16 ----------------
__global__ void k_f32_to_f16(const float4* __restrict__ x,
                             ushort4* __restrict__ o, int n4) {
  int i = blockIdx.x * 256 + threadIdx.x;
  if (i >= n4) return;
  float4 v = x[i];
  __half h0 = __float2half(v.x), h1 = __float2half(v.y);
  __half h2v = __float2half(v.z), h3 = __float2half(v.w);
  ushort4 r;
  r.x = *(unsigned short*)&h0; r.y = *(unsigned short*)&h1;
  r.z = *(unsigned short*)&h2v; r.w = *(unsigned short*)&h3;
  o[i] = r;
}

// ------- repack int4 -> fp8 e4m3 (q-z), transposed to [N][K] --------------
// (q-z) in [-15,15] is EXACT in e4m3. Scale applied later in GEMM staging.
__global__ void k_repack_fp8(const int* __restrict__ qw,
                             const int* __restrict__ qz,
                             unsigned char* __restrict__ bq,
                             int K, int N) {
  __shared__ __align__(16) unsigned char tile[64][80];  // [n][k], 80%16==0
  const int n0 = blockIdx.x * 64;
  const int k0 = blockIdx.y * 64;
  const int t  = threadIdx.x;
  const int Nw = N >> 3;
  const int grp = k0 >> 7;  // 64-tile always within one 128-group
  const int jj = t & 7;
  const int zword = qz[(size_t)grp * Nw + (n0 >> 3) + jj];
#pragma unroll
  for (int r = 0; r < 2; ++r) {
    const int kk = (t >> 3) + r * 32;
    const int word = qw[(size_t)(k0 + kk) * Nw + (n0 >> 3) + jj];
#pragma unroll
    for (int i = 0; i < 8; i += 2) {
      const float v0 = (float)(((word >> (4 * i)) & 0xF) - ((zword >> (4 * i)) & 0xF));
      const float v1 = (float)(((word >> (4 * i + 4)) & 0xF) - ((zword >> (4 * i + 4)) & 0xF));
      const int p = __builtin_amdgcn_cvt_pk_fp8_f32(v0, v1, 0, false);
      tile[jj * 8 + i][kk]     = (unsigned char)(p & 0xFF);
      tile[jj * 8 + i + 1][kk] = (unsigned char)((p >> 8) & 0xFF);
    }
  }
  __syncthreads();
  const int n  = t >> 2;
  const int kc = (t & 3) * 16;
  int4 v = *(const int4*)&tile[n][kc];
  *(int4*)(bq + (size_t)(n0 + n) * K + k0 + kc) = v;
}

// dequant 16 fp8 (in uint4) * s -> 16 f16 stored at 16B-aligned dst
__device__ __forceinline__ void dq16(uint4 w, float s, __half* dst) {
  h16x2 r[8];
  const unsigned int ws[4] = {w.x, w.y, w.z, w.w};
#pragma unroll
  for (int d = 0; d < 4; ++d) {
    f32x2 lo = __builtin_amdgcn_cvt_pk_f32_fp8((int)ws[d], false);
    f32x2 hi = __builtin_amdgcn_cvt_pk_f32_fp8((int)ws[d], true);
    r[d * 2]     = __builtin_amdgcn_cvt_pkrtz(lo.x * s, lo.y * s);
    r[d * 2 + 1] = __builtin_amdgcn_cvt_pkrtz(hi.x * s, hi.y * s);
  }
  *(uint4*)dst       = *(const uint4*)&r[0];
  *(uint4*)(dst + 8) = *(const uint4*)&r[4];
}

// ---------------- GEMM: C[M,N] = A[M,K] @ Bq[N,K]^T (fp8 B, f16 MFMA) -----
// R7 = the R4 frame (128x128 tile, 4 waves, 2-barrier K-loop, fp8-B reg
// dequant with cross-barrier prefetch) + the conflict fix R5/R6 validated:
//   - As is one [128 row][64 half] buffer (128B rows). 16B unit u of row r
//     is stored at u ^ (r&7): achieved by permuting the per-lane GLOBAL
//     source column (glds16 LDS dest stays linear), and applying the same
//     XOR on fragment reads. A-reads go 8-way-conflicted -> 2-way (free).
//     (R4: SQ_LDS_BANK_CONFLICT 6.76e7 ~= 24% of the critical path.)
//   - Bs rows stay padded to 40 f16 (80B) -> already conflict-free.
// EPI 0: C f16 = acc          (up -> h)
// EPI 1: C f16 = silu(acc)*C  (gate, reads u from h, writes h)
// EPI 2: C f32 = acc          (down -> d_out)
template <int EPI>
__global__ __launch_bounds__(256, 4)
void k_gemm_q(const __half* __restrict__ A,
              const unsigned char* __restrict__ Bq,
              const float* __restrict__ sc,
              void* __restrict__ Cv, int M, int N, int K) {
  __shared__ __align__(16) __half As[128 * 64];     // 16 KiB, xor-swizzled
  __shared__ __align__(16) __half Bs[2][128 * 40];  // padded: 40 f16 = 80 B rows
  // ---- grouped swizzle: bid -> (mb, nb) ----
  const int nblk = gridDim.x;
  const int bid  = blockIdx.y * nblk + blockIdx.x;
  const int GM   = 16;
  const int band_sz = GM * nblk;
  const int band = bid / band_sz;
  const int rrem = bid - band * band_sz;
  const int nb   = rrem / GM;
  const int mb   = band * GM + (rrem - nb * GM);
  const int n0 = nb * 128;
  const int m0 = mb * 128;

  const int t = threadIdx.x;
  const int w = t >> 6;
  const int lane = t & 63;
  const int quad = lane >> 4;
  const int lm = lane & 15;
  const int wm = w >> 1;
  const int wn = w & 1;
  f32x4 acc[4][4] = {};

  // A staging (glds16, xor-swizzled global source):
  // wave w covers rows [w*32, w*32+32) in 4 calls of 8 rows;
  // lane l -> (row = l>>3, unit = (l&7) ^ ((l>>3)&7)).
  const int arow_l = w * 32 + (lane >> 3);
  const int acol_l = ((lane & 7) ^ ((lane >> 3) & 7)) * 8;  // halves
  const __half* Ag = A + (size_t)(m0 + arow_l) * K + acol_l;
  const int albase = (w * 32) * 64;  // halves

  // B staging (register dequant): thread -> (row = t>>1, half = t&1)
  const int brow = t >> 1;
  const int bhalf = t & 1;
  const unsigned char* bg = Bq + (size_t)(n0 + brow) * K + bhalf * 16;
  __half* bdst0 = &Bs[0][brow * 40 + bhalf * 16];
  __half* bdst1 = &Bs[1][brow * 40 + bhalf * 16];

  // A fragment read offsets: row = wm*64 + mi*16 + lm (row&7 = lm&7),
  // global unit g = h*4 + quad, stored at g ^ (row&7).
  const int axor = lm & 7;

  float s = 0.0f;
  uint4 bc0 = *(const uint4*)(bg);        // k0=0, stage 0
  uint4 bc1 = *(const uint4*)(bg + 32);   // k0=0, stage 1

  for (int k0 = 0; k0 < K; k0 += 64) {
    if ((k0 & 127) == 0) s = sc[(size_t)(k0 >> 7) * N + n0 + brow];
    __syncthreads();  // prev fragments consumed; drains B prefetch
    glds16(Ag + k0,                    &As[albase]);
    glds16(Ag + k0 + (size_t)8 * K,    &As[albase + 512]);
    glds16(Ag + k0 + (size_t)16 * K,   &As[albase + 1024]);
    glds16(Ag + k0 + (size_t)24 * K,   &As[albase + 1536]);
    dq16(bc0, s, bdst0);
    dq16(bc1, s, bdst1);
    __syncthreads();  // drains A glds16 + ds_writes
    const int kn = (k0 + 64 < K) ? (k0 + 64) : 0;  // harmless reload on last
    bc0 = *(const uint4*)(bg + kn);        // prefetch: in flight across MFMA
    bc1 = *(const uint4*)(bg + kn + 32);
#pragma unroll
    for (int h = 0; h < 2; ++h) {
      const int auh = (((h << 2) | quad) ^ axor) * 8;  // swizzled unit (halves)
      f16x8 af[4], bfr[4];
#pragma unroll
      for (int mi = 0; mi < 4; ++mi)
        af[mi] = *(const f16x8*)&As[(wm * 64 + mi * 16 + lm) * 64 + auh];
#pragma unroll
      for (int ni = 0; ni < 4; ++ni)
        bfr[ni] = *(const f16x8*)&Bs[h][(wn * 64 + ni * 16 + lm) * 40 + quad * 8];
#pragma unroll
      for (int mi = 0; mi < 4; ++mi)
#pragma unroll
        for (int ni = 0; ni < 4; ++ni)
          acc[mi][ni] = __builtin_amdgcn_mfma_f32_16x16x32_f16(
              af[mi], bfr[ni], acc[mi][ni], 0, 0, 0);
    }
  }

  // epilogue: C/D layout col=lane&15, row=quad*4+reg
#pragma unroll
  for (int mi = 0; mi < 4; ++mi)
#pragma unroll
    for (int ni = 0; ni < 4; ++ni)
#pragma unroll
      for (int r = 0; r < 4; ++r) {
        const int row = m0 + wm * 64 + mi * 16 + quad * 4 + r;
        const int col = n0 + wn * 64 + ni * 16 + lm;
        const float v = acc[mi][ni][r];
        if (EPI == 0) {
          ((__half*)Cv)[(size_t)row * N + col] = __float2half(v);
        } else if (EPI == 1) {
          __half* H = (__half*)Cv;
          const float u = __half2float(H[(size_t)row * N + col]);
          const float sg = v / (1.0f + __expf(-v));
          H[(size_t)row * N + col] = __float2half(sg * u);
        } else {
          ((float*)Cv)[(size_t)row * N + col] = v;
        }
      }
}

extern "C" void kernel_launch(void* const* d_in, const int* in_sizes, int n_in,
                              void* d_out, int out_size, void* d_ws, size_t ws_size,
                              hipStream_t stream) {
  const float* x   = (const float*)d_in[0];
  const int*   gqw = (const int*)d_in[1];
  const float* gsc = (const float*)d_in[2];
  const int*   gqz = (const int*)d_in[3];
  const int*   uqw = (const int*)d_in[4];
  const float* usc = (const float*)d_in[5];
  const int*   uqz = (const int*)d_in[6];
  const int*   dqw = (const int*)d_in[7];
  const float* dsc = (const float*)d_in[8];
  const int*   dqz = (const int*)d_in[9];
  float* out = (float*)d_out;

  // ws layout (~169 MB):
  //   xb  : T_TOK*KDIM f16   = 33,554,432 B
  //   bq  : IDIM*KDIM  fp8   = 45,088,768 B (reused up/gate/down)
  //   h   : T_TOK*IDIM f16   = 90,177,536 B
  char* ws = (char*)d_ws;
  __half*        xb = (__half*)ws;
  unsigned char* bq = (unsigned char*)(ws + 33554432);
  __half*        h  = (__half*)(ws + 33554432 + 45088768);

  k_f32_to_f16<<<16384, 256, 0, stream>>>((const float4*)x, (ushort4*)xb,
                                          (T_TOK * KDIM) / 4);

  dim3 rpg(IDIM / 64, KDIM / 64);    // (172, 64)
  dim3 rpd(ODIM / 64, IDIM / 64);    // (64, 172)
  dim3 g1(IDIM / 128, T_TOK / 128);  // (86, 32)
  dim3 g2(ODIM / 128, T_TOK / 128);  // (32, 32)

  // up: u = x @ Wu^T  -> h (f16)
  k_repack_fp8<<<rpg, 256, 0, stream>>>(uqw, uqz, bq, KDIM, IDIM);
  k_gemm_q<0><<<g1, 256, 0, stream>>>(xb, bq, usc, (void*)h, T_TOK, IDIM, KDIM);
  // gate: h = silu(x @ Wg^T) * h
  k_repack_fp8<<<rpg, 256, 0, stream>>>(gqw, gqz, bq, KDIM, IDIM);
  k_gemm_q<1><<<g1, 256, 0, stream>>>(xb, bq, gsc, (void*)h, T_TOK, IDIM, KDIM);
  // down: out = h @ Wd^T (f32)
  k_repack_fp8<<<rpd, 256, 0, stream>>>(dqw, dqz, bq, IDIM, ODIM);
  k_gemm_q<2><<<g2, 256, 0, stream>>>(h, bq, dsc, (void*)out, T_TOK, ODIM, IDIM);
}

// Round 4
// 1336.961 us; speedup vs baseline: 1.0783x; 1.0783x over previous
//
#include <hip/hip_runtime.h>
#include <hip/hip_bf16.h>
#include <hip/hip_fp16.h>

// Problem dims (fixed for QuantLlamaMLP_549755813920)
#define T_TOK 4096   // tokens = 2*2048
#define KDIM  4096   // in_features
#define IDIM  11008  // intermediate
#define ODIM  4096   // out_features

typedef _Float16 f16x8 __attribute__((ext_vector_type(8)));
typedef __fp16   h16x2 __attribute__((ext_vector_type(2)));  // cvt_pkrtz return type
typedef float    f32x4 __attribute__((ext_vector_type(4)));
typedef float    f32x2 __attribute__((ext_vector_type(2)));

// async global->LDS, 16B per lane; LDS dest = wave-uniform base + lane*16
__device__ __forceinline__ void glds16(const void* g, void* l) {
  __builtin_amdgcn_global_load_lds(
      (const __attribute__((address_space(1))) void*)g,
      (__attribute__((address_space(3))) void*)l, 16, 0, 0);
}

// ---------------- x: f32 -> f16 ----------------
__global__ void k_f32_to_f16(const float4* __restrict__ x,
                             ushort4* __restrict__ o, int n4) {
  int i = blockIdx.x * 256 + threadIdx.x;
  if (i >= n4) return;
  float4 v = x[i];
  __half h0 = __float2half(v.x), h1 = __float2half(v.y);
  __half h2v = __float2half(v.z), h3 = __float2half(v.w);
  ushort4 r;
  r.x = *(unsigned short*)&h0; r.y = *(unsigned short*)&h1;
  r.z = *(unsigned short*)&h2v; r.w = *(unsigned short*)&h3;
  o[i] = r;
}

// ------- repack int4 -> fp8 e4m3 (q-z), transposed to [N][K] --------------
// (q-z) in [-15,15] is EXACT in e4m3. Scale applied later in GEMM staging.
__global__ void k_repack_fp8(const int* __restrict__ qw,
                             const int* __restrict__ qz,
                             unsigned char* __restrict__ bq,
                             int K, int N) {
  __shared__ __align__(16) unsigned char tile[64][80];  // [n][k], 80%16==0
  const int n0 = blockIdx.x * 64;
  const int k0 = blockIdx.y * 64;
  const int t  = threadIdx.x;
  const int Nw = N >> 3;
  const int grp = k0 >> 7;  // 64-tile always within one 128-group
  const int jj = t & 7;
  const int zword = qz[(size_t)grp * Nw + (n0 >> 3) + jj];
#pragma unroll
  for (int r = 0; r < 2; ++r) {
    const int kk = (t >> 3) + r * 32;
    const int word = qw[(size_t)(k0 + kk) * Nw + (n0 >> 3) + jj];
#pragma unroll
    for (int i = 0; i < 8; i += 2) {
      const float v0 = (float)(((word >> (4 * i)) & 0xF) - ((zword >> (4 * i)) & 0xF));
      const float v1 = (float)(((word >> (4 * i + 4)) & 0xF) - ((zword >> (4 * i + 4)) & 0xF));
      const int p = __builtin_amdgcn_cvt_pk_fp8_f32(v0, v1, 0, false);
      tile[jj * 8 + i][kk]     = (unsigned char)(p & 0xFF);
      tile[jj * 8 + i + 1][kk] = (unsigned char)((p >> 8) & 0xFF);
    }
  }
  __syncthreads();
  const int n  = t >> 2;
  const int kc = (t & 3) * 16;
  int4 v = *(const int4*)&tile[n][kc];
  *(int4*)(bq + (size_t)(n0 + n) * K + k0 + kc) = v;
}

// dequant 16 fp8 (in uint4) * s -> 16 f16 stored at 16B-aligned dst
__device__ __forceinline__ void dq16(uint4 w, float s, __half* dst) {
  h16x2 r[8];
  const unsigned int ws[4] = {w.x, w.y, w.z, w.w};
#pragma unroll
  for (int d = 0; d < 4; ++d) {
    f32x2 lo = __builtin_amdgcn_cvt_pk_f32_fp8((int)ws[d], false);
    f32x2 hi = __builtin_amdgcn_cvt_pk_f32_fp8((int)ws[d], true);
    r[d * 2]     = __builtin_amdgcn_cvt_pkrtz(lo.x * s, lo.y * s);
    r[d * 2 + 1] = __builtin_amdgcn_cvt_pkrtz(hi.x * s, hi.y * s);
  }
  *(uint4*)dst       = *(const uint4*)&r[0];
  *(uint4*)(dst + 8) = *(const uint4*)&r[4];
}

// ====== R8: 256x256 tile, 8 waves, 4-phase K-loop with counted vmcnt ======
// Schedule per K-tile u (consuming buf CUR, staging tile u+1 into buf NXT):
//  p0: ds_read af[0-3]+bf[0-1] (12) | issue {s,bc0,bc1}(u+1) + glds A-chunks
//      0,2 (rows 0-63,128-191) -> bar,lgkm -> MFMA(mi0-3,ni0-1) -> bar
//  p1: ds_read bf[2-3] (4)         -> bar,lgkm -> MFMA(mi0-3,ni2-3)
//      -> vmcnt(5)  [= A-chunks 1,3 of tile u landed] -> bar
//  p2: ds_read af[4-7] (8)         -> bar,lgkm -> MFMA(mi4-7,ni0-1)
//      + dq16#0 -> Bs[NXT]         -> bar
//  p3: issue glds A-chunks 1,3     -> bar,lgkm -> MFMA(mi4-7,ni2-3)
//      + dq16#1 -> vmcnt(2)+lgkm(0) [= A-chunks 0,2 (u+1) landed, dq writes
//      drained] -> bar   (publishes tile u+1; never drains vmcnt to 0)
// Ledger per tile: p0 issues 5 (s,bc0,bc1,glds x2), p3 issues 2 (glds x2).
// Steady outstanding at tile entry = 2 (A-chunks 1,3 of current tile).
// A: [256][64] halves xor-swizzled (16B unit u of row r at u^(r&7), via
//    pre-swizzled glds SOURCE, linear dest; reads apply same xor) -> free.
// B: fp8 reg-staged, dequant inside p2/p3 MFMA clusters, rows padded to
//    72 halves (144 B) -> conflict-free reads/writes.
template <int EPI>
__global__ __launch_bounds__(512, 1)
void k_gemm_q(const __half* __restrict__ A,
              const unsigned char* __restrict__ Bq,
              const float* __restrict__ sc,
              void* __restrict__ Cv, int M, int N, int K) {
  __shared__ __align__(16) __half As[2][256 * 64];   // 64 KiB, xor-swizzled
  __shared__ __align__(16) __half Bs[2][256 * 72];   // 72 KiB, padded rows

  const int ntiles = K >> 6;  // 64 (up/gate) or 172 (down); always even

  // ---- XCD bijective swizzle (grid%8==0), mb-fastest ----
  const int cpx = gridDim.x >> 3;
  const int bid = blockIdx.x;
  const int s2  = (bid & 7) * cpx + (bid >> 3);
  const int mb  = s2 & 15;   // M/256 = 16 always
  const int nb  = s2 >> 4;
  const int m0 = mb << 8;
  const int n0 = nb << 8;

  const int t = threadIdx.x;
  const int w = t >> 6;         // wave 0..7
  const int lane = t & 63;
  const int quad = lane >> 4;
  const int lm = lane & 15;
  const int wm = w >> 2;        // 0..1  (row half: 128 rows)
  const int wn = w & 3;         // 0..3  (col quarter: 64 cols)

  f32x4 acc[8][4] = {};

  // ---- A glds staging: chunk c (64 rows), wave w rows c*64+w*8..+8 ----
  const int arow_l = w * 8 + (lane >> 3);
  const int acol_l = ((lane & 7) ^ ((lane >> 3) & 7)) * 8;  // halves
  const __half* Agl = A + (size_t)(m0 + arow_l) * K + acol_l;

  // ---- B reg staging: thread -> (row = t>>1, 32B-half = t&1) ----
  const int brow = t >> 1;
  const int bhalf = t & 1;
  const unsigned char* bgl = Bq + (size_t)(n0 + brow) * K + bhalf * 32;
  const float* spl = sc + n0 + brow;
  __half* bwr0 = &Bs[0][brow * 72 + bhalf * 32];
  __half* bwr1 = &Bs[1][brow * 72 + bhalf * 32];

  // ---- fragment read offsets ----
  const int axor = lm & 7;
  const int arb = (wm * 128 + lm) * 64;        // halves
  const int au0 = (quad ^ axor) * 8;           // kh=0 swizzled unit (halves)
  const int au1 = au0 ^ 32;                    // kh=1
  const int brb = (wn * 64 + lm) * 72;         // halves

#define MFQUAD(MI0, NI0)                                                   \
    _Pragma("unroll")                                                      \
    for (int mi = 0; mi < 4; ++mi) {                                       \
      _Pragma("unroll")                                                    \
      for (int ni = 0; ni < 2; ++ni) {                                     \
        acc[(MI0)+mi][(NI0)+ni] = __builtin_amdgcn_mfma_f32_16x16x32_f16(  \
            af[mi][0], bf[(NI0)+ni][0], acc[(MI0)+mi][(NI0)+ni], 0, 0, 0); \
        acc[(MI0)+mi][(NI0)+ni] = __builtin_amdgcn_mfma_f32_16x16x32_f16(  \
            af[mi][1], bf[(NI0)+ni][1], acc[(MI0)+mi][(NI0)+ni], 0, 0, 0); \
      }                                                                    \
    }

#define SBAR0 __builtin_amdgcn_sched_barrier(0)
#define BARR  __builtin_amdgcn_s_barrier()
#define LGKM0 do { asm volatile("s_waitcnt lgkmcnt(0)" ::: "memory"); SBAR0; } while (0)

#define GTILE(ASC, BSC, ASN, BWN, TN, GI) do {                             \
    f16x8 af[4][2], bf[4][2];                                              \
    /* -------- p0 -------- */                                             \
    _Pragma("unroll")                                                      \
    for (int mi = 0; mi < 4; ++mi) {                                       \
      af[mi][0] = *(const f16x8*)&(ASC)[arb + mi * 1024 + au0];            \
      af[mi][1] = *(const f16x8*)&(ASC)[arb + mi * 1024 + au1];            \
    }                                                                      \
    _Pragma("unroll")                                                      \
    for (int ni = 0; ni < 2; ++ni) {                                       \
      bf[ni][0] = *(const f16x8*)&(BSC)[brb + ni * 1152 + quad * 8];       \
      bf[ni][1] = *(const f16x8*)&(BSC)[brb + ni * 1152 + 32 + quad * 8];  \
    }                                                                      \
    s   = spl[(size_t)(GI) * N];                                           \
    bc0 = *(const uint4*)(bgl + (size_t)(TN) * 64);                        \
    bc1 = *(const uint4*)(bgl + (size_t)(TN) * 64 + 16);                   \
    glds16(Agl + (size_t)(TN) * 64,                   (ASN) + (w * 8) * 64);        \
    glds16(Agl + (size_t)(TN) * 64 + (size_t)128 * K, (ASN) + (128 + w * 8) * 64);  \
    SBAR0; BARR; LGKM0;                                                    \
    __builtin_amdgcn_s_setprio(1);                                         \
    MFQUAD(0, 0);                                                          \
    __builtin_amdgcn_s_setprio(0);                                         \
    BARR;                                                                  \
    /* -------- p1 -------- */                                             \
    _Pragma("unroll")                                                      \
    for (int ni = 0; ni < 2; ++ni) {                                       \
      bf[2+ni][0] = *(const f16x8*)&(BSC)[brb + (2+ni) * 1152 + quad * 8]; \
      bf[2+ni][1] = *(const f16x8*)&(BSC)[brb + (2+ni) * 1152 + 32 + quad * 8]; \
    }                                                                      \
    SBAR0; BARR; LGKM0;                                                    \
    __builtin_amdgcn_s_setprio(1);                                         \
    MFQUAD(0, 2);                                                          \
    __builtin_amdgcn_s_setprio(0);                                         \
    asm volatile("s_waitcnt vmcnt(5)" ::: "memory"); SBAR0;                \
    BARR;                                                                  \
    /* -------- p2 -------- */                                             \
    _Pragma("unroll")                                                      \
    for (int mi = 0; mi < 4; ++mi) {                                       \
      af[mi][0] = *(const f16x8*)&(ASC)[arb + 4096 + mi * 1024 + au0];     \
      af[mi][1] = *(const f16x8*)&(ASC)[arb + 4096 + mi * 1024 + au1];     \
    }                                                                      \
    SBAR0; BARR; LGKM0;                                                    \
    __builtin_amdgcn_s_setprio(1);                                         \
    dq16(bc0, s, (BWN));                                                   \
    MFQUAD(4, 0);                                                          \
    __builtin_amdgcn_s_setprio(0);                                         \
    BARR;                                                                  \
    /* -------- p3 -------- */                                             \
    glds16(Agl + (size_t)(TN) * 64 + (size_t)64 * K,  (ASN) + (64 + w * 8) * 64);   \
    glds16(Agl + (size_t)(TN) * 64 + (size_t)192 * K, (ASN) + (192 + w * 8) * 64);  \
    SBAR0; BARR; LGKM0;                                                    \
    __builtin_amdgcn_s_setprio(1);                                         \
    dq16(bc1, s, (BWN) + 16);                                              \
    MFQUAD(4, 2);                                                          \
    __builtin_amdgcn_s_setprio(0);                                         \
    asm volatile("s_waitcnt vmcnt(2) lgkmcnt(0)" ::: "memory"); SBAR0;     \
    BARR;                                                                  \
  } while (0)

  float s;
  uint4 bc0, bc1;

  // ---- prologue: stage tile 0 fully; enter steady state (2 outstanding) --
  {
    float s0 = spl[0];
    uint4 q0 = *(const uint4*)(bgl);
    uint4 q1 = *(const uint4*)(bgl + 16);
    SBAR0;
    glds16(Agl,                  As[0] + (w * 8) * 64);        // chunk 0
    glds16(Agl + (size_t)128 * K, As[0] + (128 + w * 8) * 64); // chunk 2
    glds16(Agl + (size_t)64 * K,  As[0] + (64 + w * 8) * 64);  // chunk 1
    glds16(Agl + (size_t)192 * K, As[0] + (192 + w * 8) * 64); // chunk 3
    SBAR0;
    asm volatile("s_waitcnt vmcnt(4)" ::: "memory"); SBAR0;    // s0,q0,q1 in
    dq16(q0, s0, bwr0);
    dq16(q1, s0, bwr0 + 16);
    asm volatile("s_waitcnt vmcnt(2) lgkmcnt(0)" ::: "memory"); SBAR0;
    BARR;
  }

  for (int pt = 0; pt < ntiles; pt += 2) {
    const int t1 = pt + 1;                                  // stage target of even tile
    const int t2 = (pt + 2 < ntiles) ? pt + 2 : ntiles - 1; // stage target of odd tile
    GTILE(As[0], Bs[0], As[1], bwr1, t1, (t1 >> 1));
    GTILE(As[1], Bs[1], As[0], bwr0, t2, (t2 >> 1));
  }

  // ---- epilogue: C/D layout col = lane&15, row = quad*4 + reg ----
#pragma unroll
  for (int mi = 0; mi < 8; ++mi)
#pragma unroll
    for (int ni = 0; ni < 4; ++ni)
#pragma unroll
      for (int r = 0; r < 4; ++r) {
        const int row = m0 + wm * 128 + mi * 16 + quad * 4 + r;
        const int col = n0 + wn * 64 + ni * 16 + lm;
        const float v = acc[mi][ni][r];
        if (EPI == 0) {
          ((__half*)Cv)[(size_t)row * N + col] = __float2half(v);
        } else if (EPI == 1) {
          __half* H = (__half*)Cv;
          const float u = __half2float(H[(size_t)row * N + col]);
          const float sg = v / (1.0f + __expf(-v));
          H[(size_t)row * N + col] = __float2half(sg * u);
        } else {
          ((float*)Cv)[(size_t)row * N + col] = v;
        }
      }
#undef MFQUAD
#undef SBAR0
#undef BARR
#undef LGKM0
#undef GTILE
}

extern "C" void kernel_launch(void* const* d_in, const int* in_sizes, int n_in,
                              void* d_out, int out_size, void* d_ws, size_t ws_size,
                              hipStream_t stream) {
  const float* x   = (const float*)d_in[0];
  const int*   gqw = (const int*)d_in[1];
  const float* gsc = (const float*)d_in[2];
  const int*   gqz = (const int*)d_in[3];
  const int*   uqw = (const int*)d_in[4];
  const float* usc = (const float*)d_in[5];
  const int*   uqz = (const int*)d_in[6];
  const int*   dqw = (const int*)d_in[7];
  const float* dsc = (const float*)d_in[8];
  const int*   dqz = (const int*)d_in[9];
  float* out = (float*)d_out;

  // ws layout (~169 MB): xb (f16 x), bq (fp8 repack), h (f16 intermediate)
  char* ws = (char*)d_ws;
  __half*        xb = (__half*)ws;
  unsigned char* bq = (unsigned char*)(ws + 33554432);
  __half*        h  = (__half*)(ws + 33554432 + 45088768);

  k_f32_to_f16<<<16384, 256, 0, stream>>>((const float4*)x, (ushort4*)xb,
                                          (T_TOK * KDIM) / 4);

  dim3 rpg(IDIM / 64, KDIM / 64);    // (172, 64)
  dim3 rpd(ODIM / 64, IDIM / 64);    // (64, 172)
  const int g1 = (T_TOK / 256) * (IDIM / 256);  // 16*43 = 688 (%8==0)
  const int g2 = (T_TOK / 256) * (ODIM / 256);  // 16*16 = 256 (%8==0)

  // up: u = x @ Wu^T  -> h (f16)
  k_repack_fp8<<<rpg, 256, 0, stream>>>(uqw, uqz, bq, KDIM, IDIM);
  k_gemm_q<0><<<g1, 512, 0, stream>>>(xb, bq, usc, (void*)h, T_TOK, IDIM, KDIM);
  // gate: h = silu(x @ Wg^T) * h
  k_repack_fp8<<<rpg, 256, 0, stream>>>(gqw, gqz, bq, KDIM, IDIM);
  k_gemm_q<1><<<g1, 512, 0, stream>>>(xb, bq, gsc, (void*)h, T_TOK, IDIM, KDIM);
  // down: out = h @ Wd^T (f32)
  k_repack_fp8<<<rpd, 256, 0, stream>>>(dqw, dqz, bq, IDIM, ODIM);
  k_gemm_q<2><<<g2, 512, 0, stream>>>(h, bq, dsc, (void*)out, T_TOK, ODIM, IDIM);
}